// Round 14
// baseline (405.738 us; speedup 1.0000x reference)
//
#include <hip/hip_runtime.h>

#define DIM   512
#define LSEQ  4096
#define BATCH 8
#define NTOK  (BATCH * LSEQ)   // 32768
#define NCHUNK 4
#define MCH   (NTOK / NCHUNK)  // 8192 tokens per chunk (qkv/attn)
#define FCH   (NTOK / 2)       // 16384 tokens per chunk (ffn, = 4 batches)

typedef __bf16 bf16_t;
typedef bf16_t bf16x8 __attribute__((ext_vector_type(8)));
typedef float  f32x4  __attribute__((ext_vector_type(4)));

__device__ __forceinline__ unsigned short f2bf(float f) {
  unsigned u = __builtin_bit_cast(unsigned, f);
  unsigned r = u + 0x7fffu + ((u >> 16) & 1u);   // RNE
  return (unsigned short)(r >> 16);
}
__device__ __forceinline__ float bf2f(unsigned short s) {
  return __builtin_bit_cast(float, ((unsigned)s) << 16);
}
__device__ __forceinline__ bf16x8 ld_frag(const unsigned short* p) {
  uint4 v = *reinterpret_cast<const uint4*>(p);
  return __builtin_bit_cast(bf16x8, v);
}
__device__ __forceinline__ void gload16(const unsigned short* g, unsigned short* l) {
  __builtin_amdgcn_global_load_lds(
      (const __attribute__((address_space(1))) unsigned int*)(const void*)g,
      (__attribute__((address_space(3))) unsigned int*)(void*)l, 16, 0, 0);
}

// ---------------- weight prep: W[K][N] f32 -> tiles [kt][nb][128][64] bf16,
// pre-swizzled so a flat copy into LDS yields Bs[nn*64 + (k ^ ((nn&7)<<3))].
__global__ __launch_bounds__(256) void prep_w(
    const float* __restrict__ W, unsigned short* __restrict__ out,
    int N, int NB, int ffn1) {
  const int idx = blockIdx.x * 256 + threadIdx.x;   // K*N/8 threads
  const int j0 = (idx & 7) * 8;
  const int nn = (idx >> 3) & 127;
  const int nbkt = idx >> 10;          // = kt*NB + nb
  const int nb = nbkt % NB;
  const int kt = nbkt / NB;
  int wcol;
  if (ffn1) {
    int isg = (nn >> 5) & 1;
    int gcol = ((nn >> 6) << 5) + (((nn >> 4) & 1) << 4) + (nn & 15);
    wcol = isg * 1024 + nb * 64 + gcol;
  } else {
    wcol = nb * 128 + nn;
  }
  const int s = (nn & 7) << 3;
  union { unsigned short us[8]; uint4 u; } r;
#pragma unroll
  for (int t = 0; t < 8; ++t) {
    int row = kt * 64 + ((j0 ^ s) + t);
    r.us[t] = f2bf(W[(size_t)row * N + wcol]);
  }
  *reinterpret_cast<uint4*>(out + (size_t)nbkt * 8192 + nn * 64 + j0) = r.u;
}

// ---------------- transpose in: x[B][512][4096] f32 -> xt[B][4096][512] bf16
__global__ __launch_bounds__(256) void transpose_in(
    const float* __restrict__ in, unsigned short* __restrict__ out) {
  __shared__ float tile[64][65];
  const int b = blockIdx.z;
  const int r0 = blockIdx.y * 64, c0 = blockIdx.x * 64;   // r: dim, c: tok
  const float* ip = in + ((size_t)b * 512 + r0) * 4096 + c0;
#pragma unroll
  for (int i = 0; i < 16; ++i) {
    int flat = i * 256 + threadIdx.x;
    int r = flat >> 6, c = flat & 63;
    tile[r][c] = ip[(size_t)r * 4096 + c];
  }
  __syncthreads();
#pragma unroll
  for (int i = 0; i < 16; ++i) {
    int flat = i * 256 + threadIdx.x;
    int r = flat >> 6, c = flat & 63;   // r: tok, c: dim
    out[((size_t)b * 4096 + c0 + r) * 512 + r0 + c] = f2bf(tile[c][r]);
  }
}

// ---------------- GEMM 256x256 tile, 512 thr, 8 waves (4 row-bands x 2) ---
// C = A[MxK](bf16) @ Wt + bias; optionally (*scale + bias2 + res). Out bf16.
// 64 MFMA per wave per K-tile; 64 KB LDS single-buffered (2 blocks/CU).
template <bool SCALERES>
__global__ __launch_bounds__(512, 2) void gemm256(
    const unsigned short* __restrict__ A, const unsigned short* __restrict__ Wt,
    const float* __restrict__ bias, const float* __restrict__ scale,
    const float* __restrict__ bias2, const unsigned short* __restrict__ res,
    unsigned short* __restrict__ Cout, int N, int K, int nxb) {
  __shared__ unsigned short As[256 * 64];   // 32 KB
  __shared__ unsigned short Bs[256 * 64];   // 32 KB
  const int tid = threadIdx.x, lane = tid & 63, wave = tid >> 6;
  const int l15 = lane & 15, hi8 = (lane >> 4) * 8;
  const int wm = wave >> 1, wn = wave & 1;
  const int cpx = gridDim.x >> 3;
  const int sid = (blockIdx.x & 7) * cpx + (blockIdx.x >> 3);
  const int by = sid / nxb, bx = sid - by * nxb;
  const int row0 = by * 256, col0 = bx * 256;
  const int NB = N >> 7;

  const unsigned short* abase =
      A + (size_t)(row0 + (lane >> 3)) * K + 8 * ((lane & 7) ^ (lane >> 3));

  f32x4 acc[4][8] = {};

  for (int kt6 = 0; kt6 < (K >> 6); ++kt6) {
#pragma unroll
    for (int c = 0; c < 4; ++c) {          // A: 32 chunks / 8 waves
      const int ch = c * 8 + wave;
      gload16(abase + (size_t)(ch * 8) * K + kt6 * 64, &As[ch * 512]);
    }
#pragma unroll
    for (int c = 0; c < 4; ++c) {          // B: 32 chunks / 8 waves
      const int cb = c * 8 + wave;
      gload16(Wt + ((size_t)kt6 * NB + 2 * bx + (cb >> 4)) * 8192 + (cb & 15) * 512 + lane * 8,
              &Bs[cb * 512]);
    }
    __syncthreads();
#pragma unroll
    for (int kk = 0; kk < 2; ++kk) {
      const int kbs = kk * 32 + hi8;
      bf16x8 af[4], bfr[8];
#pragma unroll
      for (int m = 0; m < 4; ++m) {
        int r = wm * 64 + m * 16 + l15;
        af[m] = ld_frag(&As[r * 64 + (kbs ^ ((r & 7) << 3))]);
      }
#pragma unroll
      for (int n = 0; n < 8; ++n) {
        int cn = wn * 128 + n * 16 + l15;
        bfr[n] = ld_frag(&Bs[cn * 64 + (kbs ^ ((cn & 7) << 3))]);
      }
#pragma unroll
      for (int m = 0; m < 4; ++m)
#pragma unroll
        for (int n = 0; n < 8; ++n)
          acc[m][n] = __builtin_amdgcn_mfma_f32_16x16x32_bf16(
              af[m], bfr[n], acc[m][n], 0, 0, 0);
    }
    __syncthreads();
  }
#pragma unroll
  for (int m = 0; m < 4; ++m) {
#pragma unroll
    for (int n = 0; n < 8; ++n) {
      const int col = col0 + wn * 128 + n * 16 + l15;
      const float b1 = bias[col];
      float sc = 1.f, b2 = 0.f;
      if constexpr (SCALERES) { sc = scale[col]; b2 = bias2[col]; }
#pragma unroll
      for (int r = 0; r < 4; ++r) {
        const int row = row0 + wm * 64 + m * 16 + (lane >> 4) * 4 + r;
        float v = acc[m][n][r] + b1;
        if constexpr (SCALERES) {
          v = v * sc + b2;
          v += bf2f(res[(size_t)row * N + col]);
        }
        Cout[(size_t)row * N + col] = f2bf(v);
      }
    }
  }
}

// ---------------- FFN1 + GLU fused, 256x256 tile, 8 waves (4x2) -----------
// (unchanged from R13 — the verified winner)
__global__ __launch_bounds__(512, 2) void ffn1glu_kernel(
    const unsigned short* __restrict__ A, const unsigned short* __restrict__ Wt,
    const float* __restrict__ b1, unsigned short* __restrict__ g, int nxb) {
  __shared__ unsigned short As[256 * 64];   // 32 KB
  __shared__ unsigned short Bs[256 * 64];   // 32 KB
  const int tid = threadIdx.x, lane = tid & 63, wave = tid >> 6;
  const int l15 = lane & 15, hi8 = (lane >> 4) * 8;
  const int wm = wave >> 1, wn = wave & 1;
  const int cpx = gridDim.x >> 3;
  const int sid = (blockIdx.x & 7) * cpx + (blockIdx.x >> 3);
  const int by = sid / nxb, bx = sid - by * nxb;
  const int row0 = by * 256;
  const int K = 512, NB = 16;

  const unsigned short* abase =
      A + (size_t)(row0 + (lane >> 3)) * K + 8 * ((lane & 7) ^ (lane >> 3));

  f32x4 acc[4][8] = {};

  for (int kt6 = 0; kt6 < K / 64; ++kt6) {
#pragma unroll
    for (int c = 0; c < 4; ++c) {
      const int ch = c * 8 + wave;
      gload16(abase + (size_t)(ch * 8) * K + kt6 * 64, &As[ch * 512]);
    }
#pragma unroll
    for (int c = 0; c < 4; ++c) {
      const int cb = c * 8 + wave;
      gload16(Wt + ((size_t)kt6 * NB + 2 * bx + (cb >> 4)) * 8192 + (cb & 15) * 512 + lane * 8,
              &Bs[cb * 512]);
    }
    __syncthreads();
#pragma unroll
    for (int kk = 0; kk < 2; ++kk) {
      const int kbs = kk * 32 + hi8;
      bf16x8 af[4], bfr[8];
#pragma unroll
      for (int m = 0; m < 4; ++m) {
        int r = wm * 64 + m * 16 + l15;
        af[m] = ld_frag(&As[r * 64 + (kbs ^ ((r & 7) << 3))]);
      }
#pragma unroll
      for (int n = 0; n < 8; ++n) {
        int cn = wn * 128 + n * 16 + l15;
        bfr[n] = ld_frag(&Bs[cn * 64 + (kbs ^ ((cn & 7) << 3))]);
      }
#pragma unroll
      for (int m = 0; m < 4; ++m)
#pragma unroll
        for (int n = 0; n < 8; ++n)
          acc[m][n] = __builtin_amdgcn_mfma_f32_16x16x32_bf16(
              af[m], bfr[n], acc[m][n], 0, 0, 0);
    }
    __syncthreads();
  }
  // wave's W-tile = prep nb (2bx+wn); out rows nn in {0-31,64-95} (n 0,1,4,5),
  // gate at nn+32 (n+2). g-col = (2bx+wn)*64 + sub.
#pragma unroll
  for (int m = 0; m < 4; ++m) {
#pragma unroll
    for (int np = 0; np < 4; ++np) {
      const int n = (np & 1) + (np >> 1) * 4;       // 0,1,4,5
      const int sub = ((n & 4) ? 32 : 0) + (n & 1) * 16 + l15;
      const int gc = (2 * bx + wn) * 64 + sub;
      const float bo = b1[gc];
      const float bg = b1[1024 + gc];
#pragma unroll
      for (int r = 0; r < 4; ++r) {
        const int row = row0 + wm * 64 + m * 16 + (lane >> 4) * 4 + r;
        float o  = acc[m][n][r] + bo;
        float ga = acc[m][n + 2][r] + bg;
        float s  = ga / (1.f + __expf(-ga));
        g[(size_t)row * 1024 + gc] = f2bf(o * s);
      }
    }
  }
}

// ---------------- block-local attention, one (blk-of-64-tokens, head) per WG
__global__ __launch_bounds__(256) void attn_kernel(
    const unsigned short* __restrict__ qkv, unsigned short* __restrict__ out) {
  __shared__ unsigned short Qs[64 * 64];
  __shared__ unsigned short Ks[64 * 64];
  __shared__ unsigned short Vs[64 * 64];  // [d][key]
  __shared__ unsigned short Ps[64 * 64];
  const int id = blockIdx.x;
  const int h = id & 7, blk = id >> 3;
  const size_t tok0 = (size_t)blk * 64;
  const unsigned short* base = qkv + tok0 * 1536 + h * 192;
  const int tid = threadIdx.x, lane = tid & 63, wave = tid >> 6;

#pragma unroll
  for (int i = 0; i < 2; ++i) {
    int flat = i * 2048 + tid * 8;
    int r = flat >> 6, c = flat & 63;
    const unsigned short* p = base + (size_t)r * 1536 + c;
    uint4 q8 = *reinterpret_cast<const uint4*>(p);
    uint4 k8 = *reinterpret_cast<const uint4*>(p + 64);
    uint4 v8 = *reinterpret_cast<const uint4*>(p + 128);
    int us = r * 64 + (c ^ ((r & 7) << 3));
    *reinterpret_cast<uint4*>(&Qs[us]) = q8;
    *reinterpret_cast<uint4*>(&Ks[us]) = k8;
    const unsigned short* ve = reinterpret_cast<const unsigned short*>(&v8);
#pragma unroll
    for (int j = 0; j < 8; ++j) {
      int d = c + j;
      Vs[d * 64 + (r ^ ((d & 7) << 3))] = ve[j];
    }
  }
  __syncthreads();

  f32x4 sacc[4] = {};
#pragma unroll
  for (int kk = 0; kk < 64; kk += 32) {
    const int kb = kk + (lane >> 4) * 8;
    const int rq = wave * 16 + (lane & 15);
    bf16x8 aq = ld_frag(&Qs[rq * 64 + (kb ^ ((rq & 7) << 3))]);
#pragma unroll
    for (int n = 0; n < 4; ++n) {
      const int rk = n * 16 + (lane & 15);
      bf16x8 bk = ld_frag(&Ks[rk * 64 + (kb ^ ((rk & 7) << 3))]);
      sacc[n] = __builtin_amdgcn_mfma_f32_16x16x32_bf16(aq, bk, sacc[n], 0, 0, 0);
    }
  }
#pragma unroll
  for (int r = 0; r < 4; ++r) {
    float mx = -1e30f;
#pragma unroll
    for (int n = 0; n < 4; ++n) mx = fmaxf(mx, sacc[n][r]);
#pragma unroll
    for (int msk = 1; msk < 16; msk <<= 1) mx = fmaxf(mx, __shfl_xor(mx, msk));
    float sum = 0.f;
#pragma unroll
    for (int n = 0; n < 4; ++n) {
      float e = __expf((sacc[n][r] - mx) * 0.125f);
      sacc[n][r] = e;
      sum += e;
    }
#pragma unroll
    for (int msk = 1; msk < 16; msk <<= 1) sum += __shfl_xor(sum, msk);
    const float inv = 1.f / sum;
    const int row = wave * 16 + (lane >> 4) * 4 + r;
#pragma unroll
    for (int n = 0; n < 4; ++n) {
      int col = n * 16 + (lane & 15);
      Ps[row * 64 + (col ^ ((row & 7) << 3))] = f2bf(sacc[n][r] * inv);
    }
  }
  __syncthreads();

  f32x4 oacc[4] = {};
#pragma unroll
  for (int kk = 0; kk < 64; kk += 32) {
    const int kb = kk + (lane >> 4) * 8;
    const int rp = wave * 16 + (lane & 15);
    bf16x8 ap = ld_frag(&Ps[rp * 64 + (kb ^ ((rp & 7) << 3))]);
#pragma unroll
    for (int n = 0; n < 4; ++n) {
      const int rv = n * 16 + (lane & 15);
      bf16x8 bv = ld_frag(&Vs[rv * 64 + (kb ^ ((rv & 7) << 3))]);
      oacc[n] = __builtin_amdgcn_mfma_f32_16x16x32_bf16(ap, bv, oacc[n], 0, 0, 0);
    }
  }
#pragma unroll
  for (int n = 0; n < 4; ++n) {
    const int col = n * 16 + (lane & 15);
#pragma unroll
    for (int r = 0; r < 4; ++r) {
      const int row = wave * 16 + (lane >> 4) * 4 + r;
      out[(tok0 + row) * 512 + h * 64 + col] = f2bf(oacc[n][r]);
    }
  }
}

// ---------------- LayerNorm over D=512 (bf16 in, bf16 out), wave/token ---
__global__ __launch_bounds__(256) void ln_kernel(
    const unsigned short* __restrict__ in, const float* __restrict__ gam,
    const float* __restrict__ bet, unsigned short* __restrict__ out) {
  const int wave = threadIdx.x >> 6, lane = threadIdx.x & 63;
  const size_t tok = (size_t)blockIdx.x * 4 + wave;
  const unsigned short* p = in + tok * DIM + lane * 8;
  uint4 raw = *reinterpret_cast<const uint4*>(p);
  const unsigned short* us = reinterpret_cast<const unsigned short*>(&raw);
  float x[8];
#pragma unroll
  for (int j = 0; j < 8; ++j) x[j] = bf2f(us[j]);
  float s = 0.f;
#pragma unroll
  for (int j = 0; j < 8; ++j) s += x[j];
#pragma unroll
  for (int m = 1; m < 64; m <<= 1) s += __shfl_xor(s, m);
  const float mean = s * (1.f / 512.f);
  float vr = 0.f;
#pragma unroll
  for (int j = 0; j < 8; ++j) { x[j] -= mean; vr += x[j] * x[j]; }
#pragma unroll
  for (int m = 1; m < 64; m <<= 1) vr += __shfl_xor(vr, m);
  const float rs = rsqrtf(vr * (1.f / 512.f) + 1e-5f);
  alignas(16) float gv[8], bv[8];
  *reinterpret_cast<float4*>(&gv[0]) = *reinterpret_cast<const float4*>(gam + lane * 8);
  *reinterpret_cast<float4*>(&gv[4]) = *reinterpret_cast<const float4*>(gam + lane * 8 + 4);
  *reinterpret_cast<float4*>(&bv[0]) = *reinterpret_cast<const float4*>(bet + lane * 8);
  *reinterpret_cast<float4*>(&bv[4]) = *reinterpret_cast<const float4*>(bet + lane * 8 + 4);
  union { unsigned short us[8]; uint4 u; } rr;
#pragma unroll
  for (int j = 0; j < 8; ++j) rr.us[j] = f2bf(x[j] * rs * gv[j] + bv[j]);
  unsigned short* q = out + tok * DIM + lane * 8;
  *reinterpret_cast<uint4*>(q) = rr.u;
}

// ---------------- LN2 stats (per-chunk): per-token mean & rstd -----------
__global__ __launch_bounds__(256) void ln_stats(
    const unsigned short* __restrict__ in, float2* __restrict__ stats) {
  const int wave = threadIdx.x >> 6, lane = threadIdx.x & 63;
  const size_t tok = (size_t)blockIdx.x * 4 + wave;
  const unsigned short* p = in + tok * DIM + lane * 8;
  uint4 raw = *reinterpret_cast<const uint4*>(p);
  const unsigned short* us = reinterpret_cast<const unsigned short*>(&raw);
  float x[8], s = 0.f;
#pragma unroll
  for (int j = 0; j < 8; ++j) { x[j] = bf2f(us[j]); s += x[j]; }
#pragma unroll
  for (int m = 1; m < 64; m <<= 1) s += __shfl_xor(s, m);
  const float mean = s * (1.f / 512.f);
  float vr = 0.f;
#pragma unroll
  for (int j = 0; j < 8; ++j) { float d = x[j] - mean; vr += d * d; }
#pragma unroll
  for (int m = 1; m < 64; m <<= 1) vr += __shfl_xor(vr, m);
  if (lane == 0) stats[tok] = make_float2(mean, rsqrtf(vr * (1.f / 512.f) + 1e-5f));
}

// ---------------- LN2-normalize + transpose (per-chunk of 4 batches):
// mres[chunk][4096][512] bf16 -> d_out[batch0+z][512][4096] f32
__global__ __launch_bounds__(256) void transpose_norm(
    const unsigned short* __restrict__ in, const float2* __restrict__ stats,
    const float* __restrict__ gam, const float* __restrict__ bet,
    float* __restrict__ out, int batch0) {
  __shared__ float tile[64][65];
  const int bz = blockIdx.z;                 // 0..3 within chunk
  const int b = batch0 + bz;                 // global batch
  const int t0 = blockIdx.y * 64, d0 = blockIdx.x * 64;  // tokens, dims
#pragma unroll
  for (int i = 0; i < 2; ++i) {
    int flat = i * 256 + threadIdx.x;       // 512 jobs: 64 rows x 8 groups
    int r = flat >> 3, cg = flat & 7;       // r: token idx, cg: 8-col group
    const size_t tokL = (size_t)bz * 4096 + t0 + r;   // chunk-local
    uint4 raw = *reinterpret_cast<const uint4*>(in + tokL * 512 + d0 + cg * 8);
    const unsigned short* us = reinterpret_cast<const unsigned short*>(&raw);
    const float2 st = stats[tokL];
    alignas(16) float gv[8], bv[8];
    *reinterpret_cast<float4*>(&gv[0]) = *reinterpret_cast<const float4*>(gam + d0 + cg * 8);
    *reinterpret_cast<float4*>(&gv[4]) = *reinterpret_cast<const float4*>(gam + d0 + cg * 8 + 4);
    *reinterpret_cast<float4*>(&bv[0]) = *reinterpret_cast<const float4*>(bet + d0 + cg * 8);
    *reinterpret_cast<float4*>(&bv[4]) = *reinterpret_cast<const float4*>(bet + d0 + cg * 8 + 4);
#pragma unroll
    for (int j = 0; j < 8; ++j)
      tile[r][cg * 8 + j] = (bf2f(us[j]) - st.x) * st.y * gv[j] + bv[j];
  }
  __syncthreads();
#pragma unroll
  for (int i = 0; i < 16; ++i) {
    int flat = i * 256 + threadIdx.x;
    int r = flat >> 6, c = flat & 63;       // r: dim idx, c: token idx
    out[((size_t)b * 512 + d0 + r) * 4096 + t0 + c] = tile[c][r];
  }
}

// -------------------------------------------------------------------------
extern "C" void kernel_launch(void* const* d_in, const int* in_sizes, int n_in,
                              void* d_out, int out_size, void* d_ws, size_t ws_size,
                              hipStream_t stream) {
  const float* x          = (const float*)d_in[0];
  const float* w_qkv      = (const float*)d_in[1];
  const float* b_qkv      = (const float*)d_in[2];
  const float* w_proj     = (const float*)d_in[3];
  const float* b_proj     = (const float*)d_in[4];
  const float* ln1_g      = (const float*)d_in[5];
  const float* ln1_b      = (const float*)d_in[6];
  const float* ln2_g      = (const float*)d_in[7];
  const float* ln2_b      = (const float*)d_in[8];
  const float* w_ffn1     = (const float*)d_in[9];
  const float* b_ffn1     = (const float*)d_in[10];
  const float* w_ffn2     = (const float*)d_in[11];
  const float* b_ffn2     = (const float*)d_in[12];
  const float* attn_scale = (const float*)d_in[13];
  const float* attn_bias  = (const float*)d_in[14];
  const float* mlp_scale  = (const float*)d_in[15];
  const float* mlp_bias   = (const float*)d_in[16];

  char* ws = (char*)d_ws;
  const size_t MiB = 1024ull * 1024ull;
  // ws plan (peak ~53.2 MiB, known-good range):
  unsigned short* wqkvT  = (unsigned short*)(ws + 0);            // 1.5 MiB
  unsigned short* wprojT = (unsigned short*)(ws + 3 * MiB / 2);  // 0.5 MiB
  unsigned short* wffn1T = (unsigned short*)(ws + 2 * MiB);      // 2 MiB
  unsigned short* wffn2T = (unsigned short*)(ws + 4 * MiB);      // 1 MiB
  unsigned short* xt     = (unsigned short*)(ws + 5 * MiB);      // 32 MiB, ->proj
  unsigned short* qkvH   = (unsigned short*)(ws + 37 * MiB);     // 24 MiB, chunk loop
  unsigned short* gbufC  = (unsigned short*)(ws + 5 * MiB);      // 32 MiB, ffn loop (xt dead)
  unsigned short* mresC  = (unsigned short*)(ws + 37 * MiB);     // 16 MiB, ffn loop
  float2*         st2    = (float2*)(ws + 53 * MiB);             // 128 KiB
  // d_out doubles as scratch (fully rewritten by transpose_norm):
  unsigned short* ares  = (unsigned short*)d_out;                       // bytes [0,32M)
  unsigned short* attnO = (unsigned short*)d_out + (size_t)NTOK * 512;  // bytes [32M,64M)
  unsigned short* hbuf  = (unsigned short*)d_out + (size_t)NTOK * 512;  // bytes [32M,64M)

  dim3 B256(256), B512(512);
  // 0. weight prep (bf16, transposed, swizzled, consumption order)
  prep_w<<<dim3(384), B256, 0, stream>>>(w_qkv,  wqkvT,  1536, 12, 0);
  prep_w<<<dim3(128), B256, 0, stream>>>(w_proj, wprojT,  512,  4, 0);
  prep_w<<<dim3(512), B256, 0, stream>>>(w_ffn1, wffn1T, 2048, 16, 1);
  prep_w<<<dim3(256), B256, 0, stream>>>(w_ffn2, wffn2T,  512,  4, 0);
  // 1. x (B,512,4096) f32 -> xt (B,4096,512) bf16
  transpose_in<<<dim3(64, 8, 8), B256, 0, stream>>>(x, xt);
  // 2+3. per-chunk: qkvH = xt_chunk @ w_qkv + b_qkv; attnO_chunk = blockattn
  for (int c = 0; c < NCHUNK; ++c) {
    gemm256<false><<<dim3(6 * (MCH / 256)), B512, 0, stream>>>(
        xt + (size_t)c * MCH * 512, wqkvT, b_qkv, nullptr, nullptr, nullptr,
        qkvH, 1536, 512, 6);
    attn_kernel<<<dim3(MCH / 64 * 8), B256, 0, stream>>>(
        qkvH, attnO + (size_t)c * MCH * 512);
  }
  // 4. ares = (attnO @ w_proj + b_proj) * attn_scale + attn_bias + xt
  gemm256<true><<<dim3(2 * (NTOK / 256)), B512, 0, stream>>>(
      attnO, wprojT, b_proj, attn_scale, attn_bias, xt, ares, 512, 512, 2);
  // 5. h = LN1(ares)   (hbuf overwrites attnO region; attnO dead)
  ln_kernel<<<dim3(NTOK / 4), B256, 0, stream>>>(ares, ln1_g, ln1_b, hbuf);
  // 6-9. per half (4 batches): ffn1+glu -> ffn2(+res) -> LN2 stats -> out
  for (int c = 0; c < 2; ++c) {
    const unsigned short* hC = hbuf + (size_t)c * FCH * 512;
    ffn1glu_kernel<<<dim3(8 * (FCH / 256)), B512, 0, stream>>>(
        hC, wffn1T, b_ffn1, gbufC, 8);
    gemm256<true><<<dim3(2 * (FCH / 256)), B512, 0, stream>>>(
        gbufC, wffn2T, b_ffn2, mlp_scale, mlp_bias, hC, mresC, 512, 1024, 2);
    ln_stats<<<dim3(FCH / 4), B256, 0, stream>>>(mresC, st2);
    transpose_norm<<<dim3(8, 64, 4), B256, 0, stream>>>(
        mresC, st2, ln2_g, ln2_b, (float*)d_out, c * 4);
  }
}

// Round 15
// 306.418 us; speedup vs baseline: 1.3241x; 1.3241x over previous
//
#include <hip/hip_runtime.h>

#define DIM   512
#define LSEQ  4096
#define BATCH 8
#define NTOK  (BATCH * LSEQ)   // 32768

typedef __bf16 bf16_t;
typedef bf16_t bf16x8 __attribute__((ext_vector_type(8)));
typedef float  f32x4  __attribute__((ext_vector_type(4)));

__device__ __forceinline__ unsigned short f2bf(float f) {
  unsigned u = __builtin_bit_cast(unsigned, f);
  unsigned r = u + 0x7fffu + ((u >> 16) & 1u);   // RNE
  return (unsigned short)(r >> 16);
}
__device__ __forceinline__ float bf2f(unsigned short s) {
  return __builtin_bit_cast(float, ((unsigned)s) << 16);
}
__device__ __forceinline__ bf16x8 ld_frag(const unsigned short* p) {
  uint4 v = *reinterpret_cast<const uint4*>(p);
  return __builtin_bit_cast(bf16x8, v);
}
__device__ __forceinline__ void gload16(const unsigned short* g, unsigned short* l) {
  __builtin_amdgcn_global_load_lds(
      (const __attribute__((address_space(1))) unsigned int*)(const void*)g,
      (__attribute__((address_space(3))) unsigned int*)(void*)l, 16, 0, 0);
}

// ---------------- weight prep: W[K][N] f32 -> tiles [kt][nb][128][64] bf16,
// pre-swizzled so a flat copy into LDS yields Bs[nn*64 + (k ^ ((nn&7)<<3))].
__global__ __launch_bounds__(256) void prep_w(
    const float* __restrict__ W, unsigned short* __restrict__ out,
    int N, int NB, int ffn1) {
  const int idx = blockIdx.x * 256 + threadIdx.x;   // K*N/8 threads
  const int j0 = (idx & 7) * 8;
  const int nn = (idx >> 3) & 127;
  const int nbkt = idx >> 10;          // = kt*NB + nb
  const int nb = nbkt % NB;
  const int kt = nbkt / NB;
  int wcol;
  if (ffn1) {
    int isg = (nn >> 5) & 1;
    int gcol = ((nn >> 6) << 5) + (((nn >> 4) & 1) << 4) + (nn & 15);
    wcol = isg * 1024 + nb * 64 + gcol;
  } else {
    wcol = nb * 128 + nn;
  }
  const int s = (nn & 7) << 3;
  union { unsigned short us[8]; uint4 u; } r;
#pragma unroll
  for (int t = 0; t < 8; ++t) {
    int row = kt * 64 + ((j0 ^ s) + t);
    r.us[t] = f2bf(W[(size_t)row * N + wcol]);
  }
  *reinterpret_cast<uint4*>(out + (size_t)nbkt * 8192 + nn * 64 + j0) = r.u;
}

// ---------------- transpose in: x[B][512][4096] f32 -> xt[B][4096][512] bf16
__global__ __launch_bounds__(256) void transpose_in(
    const float* __restrict__ in, unsigned short* __restrict__ out) {
  __shared__ float tile[64][65];
  const int b = blockIdx.z;
  const int r0 = blockIdx.y * 64, c0 = blockIdx.x * 64;   // r: dim, c: tok
  const float* ip = in + ((size_t)b * 512 + r0) * 4096 + c0;
#pragma unroll
  for (int i = 0; i < 16; ++i) {
    int flat = i * 256 + threadIdx.x;
    int r = flat >> 6, c = flat & 63;
    tile[r][c] = ip[(size_t)r * 4096 + c];
  }
  __syncthreads();
#pragma unroll
  for (int i = 0; i < 16; ++i) {
    int flat = i * 256 + threadIdx.x;
    int r = flat >> 6, c = flat & 63;   // r: tok, c: dim
    out[((size_t)b * 4096 + c0 + r) * 512 + r0 + c] = f2bf(tile[c][r]);
  }
}

// ---------------- GEMM 128x256 tile, 256 thr, 4 waves (2x2), BK=64 --------
// (R12 winner; used for qkv, proj, ffn2)
template <bool SCALERES>
__global__ __launch_bounds__(256, 2) void gemm_kernel(
    const unsigned short* __restrict__ A, const unsigned short* __restrict__ Wt,
    const float* __restrict__ bias, const float* __restrict__ scale,
    const float* __restrict__ bias2, const unsigned short* __restrict__ res,
    unsigned short* __restrict__ Cout, int N, int K, int nxb) {
  __shared__ unsigned short As[128 * 64];   // 16 KB
  __shared__ unsigned short Bs[256 * 64];   // 32 KB
  const int tid = threadIdx.x, lane = tid & 63, wave = tid >> 6;
  const int l15 = lane & 15, hi8 = (lane >> 4) * 8;
  const int wm = wave >> 1, wn = wave & 1;
  const int cpx = gridDim.x >> 3;
  const int sid = (blockIdx.x & 7) * cpx + (blockIdx.x >> 3);
  const int by = sid / nxb, bx = sid - by * nxb;
  const int row0 = by * 128, col0 = bx * 256;

  const unsigned short* abase =
      A + (size_t)(row0 + (lane >> 3)) * K + 8 * ((lane & 7) ^ (lane >> 3));
  const unsigned short* bbase = Wt + (size_t)(2 * bx) * 8192 + lane * 8;
  const size_t bstride = (size_t)(N >> 7) * 8192;

  f32x4 acc[4][8] = {};

  for (int kt = 0; kt < K; kt += 64) {
#pragma unroll
    for (int c = 0; c < 4; ++c) {
      const int ch = wave * 4 + c;
      gload16(abase + (size_t)(ch * 8) * K + kt, &As[ch * 512]);
    }
#pragma unroll
    for (int c = 0; c < 8; ++c) {
      const int cb = wave * 8 + c;
      gload16(bbase + (size_t)(kt >> 6) * bstride + cb * 512, &Bs[cb * 512]);
    }
    __syncthreads();
#pragma unroll
    for (int kk = 0; kk < 2; ++kk) {
      const int kbs = kk * 32 + hi8;
      bf16x8 af[4], bfr[8];
#pragma unroll
      for (int m = 0; m < 4; ++m) {
        int r = wm * 64 + m * 16 + l15;
        af[m] = ld_frag(&As[r * 64 + (kbs ^ ((r & 7) << 3))]);
      }
#pragma unroll
      for (int n = 0; n < 8; ++n) {
        int rb = wn * 128 + n * 16 + l15;
        bfr[n] = ld_frag(&Bs[rb * 64 + (kbs ^ ((rb & 7) << 3))]);
      }
#pragma unroll
      for (int m = 0; m < 4; ++m)
#pragma unroll
        for (int n = 0; n < 8; ++n)
          acc[m][n] = __builtin_amdgcn_mfma_f32_16x16x32_bf16(
              af[m], bfr[n], acc[m][n], 0, 0, 0);
    }
    __syncthreads();
  }
#pragma unroll
  for (int m = 0; m < 4; ++m) {
#pragma unroll
    for (int n = 0; n < 8; ++n) {
      const int col = col0 + wn * 128 + n * 16 + l15;
      const float b1 = bias[col];
      float sc = 1.f, b2 = 0.f;
      if constexpr (SCALERES) { sc = scale[col]; b2 = bias2[col]; }
#pragma unroll
      for (int r = 0; r < 4; ++r) {
        const int row = row0 + wm * 64 + m * 16 + (lane >> 4) * 4 + r;
        float v = acc[m][n][r] + b1;
        if constexpr (SCALERES) {
          v = v * sc + b2;
          v += bf2f(res[(size_t)row * N + col]);
        }
        Cout[(size_t)row * N + col] = f2bf(v);
      }
    }
  }
}

// ---------------- FFN1 + GLU fused, 128x256 W-tile (= 128 g-cols) ---------
// (R12 winner)
__global__ __launch_bounds__(256, 2) void ffn1glu_kernel(
    const unsigned short* __restrict__ A, const unsigned short* __restrict__ Wt,
    const float* __restrict__ b1, unsigned short* __restrict__ g, int nxb) {
  __shared__ unsigned short As[128 * 64];
  __shared__ unsigned short Bs[256 * 64];
  const int tid = threadIdx.x, lane = tid & 63, wave = tid >> 6;
  const int l15 = lane & 15, hi8 = (lane >> 4) * 8;
  const int wm = wave >> 1, wn = wave & 1;
  const int cpx = gridDim.x >> 3;
  const int sid = (blockIdx.x & 7) * cpx + (blockIdx.x >> 3);
  const int by = sid / nxb, bx = sid - by * nxb;
  const int row0 = by * 128;
  const int K = 512;

  const unsigned short* abase =
      A + (size_t)(row0 + (lane >> 3)) * K + 8 * ((lane & 7) ^ (lane >> 3));
  const unsigned short* bbase = Wt + (size_t)(2 * bx) * 8192 + lane * 8;
  const size_t bstride = (size_t)16 * 8192;   // NB = 2048/128 = 16

  f32x4 acc[4][8] = {};

  for (int kt = 0; kt < K; kt += 64) {
#pragma unroll
    for (int c = 0; c < 4; ++c) {
      const int ch = wave * 4 + c;
      gload16(abase + (size_t)(ch * 8) * K + kt, &As[ch * 512]);
    }
#pragma unroll
    for (int c = 0; c < 8; ++c) {
      const int cb = wave * 8 + c;
      gload16(bbase + (size_t)(kt >> 6) * bstride + cb * 512, &Bs[cb * 512]);
    }
    __syncthreads();
#pragma unroll
    for (int kk = 0; kk < 2; ++kk) {
      const int kbs = kk * 32 + hi8;
      bf16x8 af[4], bfr[8];
#pragma unroll
      for (int m = 0; m < 4; ++m) {
        int r = wm * 64 + m * 16 + l15;
        af[m] = ld_frag(&As[r * 64 + (kbs ^ ((r & 7) << 3))]);
      }
#pragma unroll
      for (int n = 0; n < 8; ++n) {
        int rb = wn * 128 + n * 16 + l15;
        bfr[n] = ld_frag(&Bs[rb * 64 + (kbs ^ ((rb & 7) << 3))]);
      }
#pragma unroll
      for (int m = 0; m < 4; ++m)
#pragma unroll
        for (int n = 0; n < 8; ++n)
          acc[m][n] = __builtin_amdgcn_mfma_f32_16x16x32_bf16(
              af[m], bfr[n], acc[m][n], 0, 0, 0);
    }
    __syncthreads();
  }
  // wave's W-tile = prep nb (2bx+wn); out rows nn in {0-31,64-95} (n 0,1,4,5),
  // gate at nn+32 (n+2). g-col = (2bx+wn)*64 + sub.
#pragma unroll
  for (int m = 0; m < 4; ++m) {
#pragma unroll
    for (int np = 0; np < 4; ++np) {
      const int n = (np & 1) + (np >> 1) * 4;       // 0,1,4,5
      const int sub = ((n & 4) ? 32 : 0) + (n & 1) * 16 + l15;
      const int gc = (2 * bx + wn) * 64 + sub;
      const float bo = b1[gc];
      const float bg = b1[1024 + gc];
#pragma unroll
      for (int r = 0; r < 4; ++r) {
        const int row = row0 + wm * 64 + m * 16 + (lane >> 4) * 4 + r;
        float o  = acc[m][n][r] + bo;
        float ga = acc[m][n + 2][r] + bg;
        float s  = ga / (1.f + __expf(-ga));
        g[(size_t)row * 1024 + gc] = f2bf(o * s);
      }
    }
  }
}

// ---------------- block-local attention, one (blk-of-64-tokens, head) per WG
__global__ __launch_bounds__(256) void attn_kernel(
    const unsigned short* __restrict__ qkv, unsigned short* __restrict__ out) {
  __shared__ unsigned short Qs[64 * 64];
  __shared__ unsigned short Ks[64 * 64];
  __shared__ unsigned short Vs[64 * 64];  // [d][key]
  __shared__ unsigned short Ps[64 * 64];
  const int id = blockIdx.x;
  const int h = id & 7, blk = id >> 3;
  const size_t tok0 = (size_t)blk * 64;
  const unsigned short* base = qkv + tok0 * 1536 + h * 192;
  const int tid = threadIdx.x, lane = tid & 63, wave = tid >> 6;

#pragma unroll
  for (int i = 0; i < 2; ++i) {
    int flat = i * 2048 + tid * 8;
    int r = flat >> 6, c = flat & 63;
    const unsigned short* p = base + (size_t)r * 1536 + c;
    uint4 q8 = *reinterpret_cast<const uint4*>(p);
    uint4 k8 = *reinterpret_cast<const uint4*>(p + 64);
    uint4 v8 = *reinterpret_cast<const uint4*>(p + 128);
    int us = r * 64 + (c ^ ((r & 7) << 3));
    *reinterpret_cast<uint4*>(&Qs[us]) = q8;
    *reinterpret_cast<uint4*>(&Ks[us]) = k8;
    const unsigned short* ve = reinterpret_cast<const unsigned short*>(&v8);
#pragma unroll
    for (int j = 0; j < 8; ++j) {
      int d = c + j;
      Vs[d * 64 + (r ^ ((d & 7) << 3))] = ve[j];
    }
  }
  __syncthreads();

  f32x4 sacc[4] = {};
#pragma unroll
  for (int kk = 0; kk < 64; kk += 32) {
    const int kb = kk + (lane >> 4) * 8;
    const int rq = wave * 16 + (lane & 15);
    bf16x8 aq = ld_frag(&Qs[rq * 64 + (kb ^ ((rq & 7) << 3))]);
#pragma unroll
    for (int n = 0; n < 4; ++n) {
      const int rk = n * 16 + (lane & 15);
      bf16x8 bk = ld_frag(&Ks[rk * 64 + (kb ^ ((rk & 7) << 3))]);
      sacc[n] = __builtin_amdgcn_mfma_f32_16x16x32_bf16(aq, bk, sacc[n], 0, 0, 0);
    }
  }
#pragma unroll
  for (int r = 0; r < 4; ++r) {
    float mx = -1e30f;
#pragma unroll
    for (int n = 0; n < 4; ++n) mx = fmaxf(mx, sacc[n][r]);
#pragma unroll
    for (int msk = 1; msk < 16; msk <<= 1) mx = fmaxf(mx, __shfl_xor(mx, msk));
    float sum = 0.f;
#pragma unroll
    for (int n = 0; n < 4; ++n) {
      float e = __expf((sacc[n][r] - mx) * 0.125f);
      sacc[n][r] = e;
      sum += e;
    }
#pragma unroll
    for (int msk = 1; msk < 16; msk <<= 1) sum += __shfl_xor(sum, msk);
    const float inv = 1.f / sum;
    const int row = wave * 16 + (lane >> 4) * 4 + r;
#pragma unroll
    for (int n = 0; n < 4; ++n) {
      int col = n * 16 + (lane & 15);
      Ps[row * 64 + (col ^ ((row & 7) << 3))] = f2bf(sacc[n][r] * inv);
    }
  }
  __syncthreads();

  f32x4 oacc[4] = {};
#pragma unroll
  for (int kk = 0; kk < 64; kk += 32) {
    const int kb = kk + (lane >> 4) * 8;
    const int rp = wave * 16 + (lane & 15);
    bf16x8 ap = ld_frag(&Ps[rp * 64 + (kb ^ ((rp & 7) << 3))]);
#pragma unroll
    for (int n = 0; n < 4; ++n) {
      const int rv = n * 16 + (lane & 15);
      bf16x8 bv = ld_frag(&Vs[rv * 64 + (kb ^ ((rv & 7) << 3))]);
      oacc[n] = __builtin_amdgcn_mfma_f32_16x16x32_bf16(ap, bv, oacc[n], 0, 0, 0);
    }
  }
#pragma unroll
  for (int n = 0; n < 4; ++n) {
    const int col = n * 16 + (lane & 15);
#pragma unroll
    for (int r = 0; r < 4; ++r) {
      const int row = wave * 16 + (lane >> 4) * 4 + r;
      out[(tok0 + row) * 512 + h * 64 + col] = f2bf(oacc[n][r]);
    }
  }
}

// ---------------- LayerNorm over D=512 (bf16 in, bf16 out), wave/token ---
__global__ __launch_bounds__(256) void ln_kernel(
    const unsigned short* __restrict__ in, const float* __restrict__ gam,
    const float* __restrict__ bet, unsigned short* __restrict__ out) {
  const int wave = threadIdx.x >> 6, lane = threadIdx.x & 63;
  const size_t tok = (size_t)blockIdx.x * 4 + wave;
  const unsigned short* p = in + tok * DIM + lane * 8;
  uint4 raw = *reinterpret_cast<const uint4*>(p);
  const unsigned short* us = reinterpret_cast<const unsigned short*>(&raw);
  float x[8];
#pragma unroll
  for (int j = 0; j < 8; ++j) x[j] = bf2f(us[j]);
  float s = 0.f;
#pragma unroll
  for (int j = 0; j < 8; ++j) s += x[j];
#pragma unroll
  for (int m = 1; m < 64; m <<= 1) s += __shfl_xor(s, m);
  const float mean = s * (1.f / 512.f);
  float vr = 0.f;
#pragma unroll
  for (int j = 0; j < 8; ++j) { x[j] -= mean; vr += x[j] * x[j]; }
#pragma unroll
  for (int m = 1; m < 64; m <<= 1) vr += __shfl_xor(vr, m);
  const float rs = rsqrtf(vr * (1.f / 512.f) + 1e-5f);
  alignas(16) float gv[8], bv[8];
  *reinterpret_cast<float4*>(&gv[0]) = *reinterpret_cast<const float4*>(gam + lane * 8);
  *reinterpret_cast<float4*>(&gv[4]) = *reinterpret_cast<const float4*>(gam + lane * 8 + 4);
  *reinterpret_cast<float4*>(&bv[0]) = *reinterpret_cast<const float4*>(bet + lane * 8);
  *reinterpret_cast<float4*>(&bv[4]) = *reinterpret_cast<const float4*>(bet + lane * 8 + 4);
  union { unsigned short us[8]; uint4 u; } rr;
#pragma unroll
  for (int j = 0; j < 8; ++j) rr.us[j] = f2bf(x[j] * rs * gv[j] + bv[j]);
  unsigned short* q = out + tok * DIM + lane * 8;
  *reinterpret_cast<uint4*>(q) = rr.u;
}

// ---------------- LN2 stats: per-token mean & rstd -----------------------
__global__ __launch_bounds__(256) void ln_stats(
    const unsigned short* __restrict__ in, float2* __restrict__ stats) {
  const int wave = threadIdx.x >> 6, lane = threadIdx.x & 63;
  const size_t tok = (size_t)blockIdx.x * 4 + wave;
  const unsigned short* p = in + tok * DIM + lane * 8;
  uint4 raw = *reinterpret_cast<const uint4*>(p);
  const unsigned short* us = reinterpret_cast<const unsigned short*>(&raw);
  float x[8], s = 0.f;
#pragma unroll
  for (int j = 0; j < 8; ++j) { x[j] = bf2f(us[j]); s += x[j]; }
#pragma unroll
  for (int m = 1; m < 64; m <<= 1) s += __shfl_xor(s, m);
  const float mean = s * (1.f / 512.f);
  float vr = 0.f;
#pragma unroll
  for (int j = 0; j < 8; ++j) { float d = x[j] - mean; vr += d * d; }
#pragma unroll
  for (int m = 1; m < 64; m <<= 1) vr += __shfl_xor(vr, m);
  if (lane == 0) stats[tok] = make_float2(mean, rsqrtf(vr * (1.f / 512.f) + 1e-5f));
}

// ---------------- LN2-normalize + transpose:
// mres[z][4096][512] bf16 -> d_out[batch0+z][512][4096] f32
__global__ __launch_bounds__(256) void transpose_norm(
    const unsigned short* __restrict__ in, const float2* __restrict__ stats,
    const float* __restrict__ gam, const float* __restrict__ bet,
    float* __restrict__ out, int batch0) {
  __shared__ float tile[64][65];
  const int bz = blockIdx.z;
  const int b = batch0 + bz;
  const int t0 = blockIdx.y * 64, d0 = blockIdx.x * 64;  // tokens, dims
#pragma unroll
  for (int i = 0; i < 2; ++i) {
    int flat = i * 256 + threadIdx.x;       // 512 jobs: 64 rows x 8 groups
    int r = flat >> 3, cg = flat & 7;       // r: token idx, cg: 8-col group
    const size_t tokL = (size_t)bz * 4096 + t0 + r;
    uint4 raw = *reinterpret_cast<const uint4*>(in + tokL * 512 + d0 + cg * 8);
    const unsigned short* us = reinterpret_cast<const unsigned short*>(&raw);
    const float2 st = stats[tokL];
    alignas(16) float gv[8], bv[8];
    *reinterpret_cast<float4*>(&gv[0]) = *reinterpret_cast<const float4*>(gam + d0 + cg * 8);
    *reinterpret_cast<float4*>(&gv[4]) = *reinterpret_cast<const float4*>(gam + d0 + cg * 8 + 4);
    *reinterpret_cast<float4*>(&bv[0]) = *reinterpret_cast<const float4*>(bet + d0 + cg * 8);
    *reinterpret_cast<float4*>(&bv[4]) = *reinterpret_cast<const float4*>(bet + d0 + cg * 8 + 4);
#pragma unroll
    for (int j = 0; j < 8; ++j)
      tile[r][cg * 8 + j] = (bf2f(us[j]) - st.x) * st.y * gv[j] + bv[j];
  }
  __syncthreads();
#pragma unroll
  for (int i = 0; i < 16; ++i) {
    int flat = i * 256 + threadIdx.x;
    int r = flat >> 6, c = flat & 63;       // r: dim idx, c: token idx
    out[((size_t)b * 512 + d0 + r) * 4096 + t0 + c] = tile[c][r];
  }
}

// -------------------------------------------------------------------------
extern "C" void kernel_launch(void* const* d_in, const int* in_sizes, int n_in,
                              void* d_out, int out_size, void* d_ws, size_t ws_size,
                              hipStream_t stream) {
  const float* x          = (const float*)d_in[0];
  const float* w_qkv      = (const float*)d_in[1];
  const float* b_qkv      = (const float*)d_in[2];
  const float* w_proj     = (const float*)d_in[3];
  const float* b_proj     = (const float*)d_in[4];
  const float* ln1_g      = (const float*)d_in[5];
  const float* ln1_b      = (const float*)d_in[6];
  const float* ln2_g      = (const float*)d_in[7];
  const float* ln2_b      = (const float*)d_in[8];
  const float* w_ffn1     = (const float*)d_in[9];
  const float* b_ffn1     = (const float*)d_in[10];
  const float* w_ffn2     = (const float*)d_in[11];
  const float* b_ffn2     = (const float*)d_in[12];
  const float* attn_scale = (const float*)d_in[13];
  const float* attn_bias  = (const float*)d_in[14];
  const float* mlp_scale  = (const float*)d_in[15];
  const float* mlp_bias   = (const float*)d_in[16];

  char* ws = (char*)d_ws;
  const size_t MiB = 1024ull * 1024ull;
  // fixed region: weights + xt
  unsigned short* wqkvT  = (unsigned short*)(ws + 0);            // 1.5 MiB
  unsigned short* wprojT = (unsigned short*)(ws + 3 * MiB / 2);  // 0.5 MiB
  unsigned short* wffn1T = (unsigned short*)(ws + 2 * MiB);      // 2 MiB
  unsigned short* wffn2T = (unsigned short*)(ws + 4 * MiB);      // 1 MiB
  unsigned short* xt     = (unsigned short*)(ws + 5 * MiB);      // 32 MiB, ->proj
  unsigned short* qkvH   = (unsigned short*)(ws + 37 * MiB);     // nq-dependent size
  // d_out doubles as scratch (fully rewritten by transpose_norm):
  unsigned short* ares  = (unsigned short*)d_out;                       // [0,32M)
  unsigned short* attnO = (unsigned short*)d_out + (size_t)NTOK * 512;  // [32M,64M)
  unsigned short* hbuf  = (unsigned short*)d_out + (size_t)NTOK * 512;  // [32M,64M)

  // ---- tiering on ws_size (fixed per process -> graph-capture safe) ----
  const bool bigws = ws_size >= 134 * MiB;  // full qkvH (96M) / gbuf(64M)+mres(32M)+st2
  const bool midws = ws_size >= 86 * MiB;   // qkvH 48M (2-chunk qkv)
  const int  nq  = bigws ? 1 : (midws ? 2 : 4);  // qkv/attn chunks
  const int  QCH = NTOK / nq;
  const int  nf  = bigws ? 1 : 2;                // ffn chunks
  const int  FCHf = NTOK / nf;
  unsigned short* gbuf = bigws ? (unsigned short*)(ws + 37 * MiB)
                               : (unsigned short*)(ws + 5 * MiB);   // xt dead by then
  unsigned short* mres = bigws ? (unsigned short*)(ws + 101 * MiB)
                               : (unsigned short*)(ws + 37 * MiB);
  float2* st2 = bigws ? (float2*)(ws + 133 * MiB) : (float2*)(ws + 53 * MiB);

  dim3 B256(256);
  // 0. weight prep (bf16, transposed, swizzled, consumption order)
  prep_w<<<dim3(384), B256, 0, stream>>>(w_qkv,  wqkvT,  1536, 12, 0);
  prep_w<<<dim3(128), B256, 0, stream>>>(w_proj, wprojT,  512,  4, 0);
  prep_w<<<dim3(512), B256, 0, stream>>>(w_ffn1, wffn1T, 2048, 16, 1);
  prep_w<<<dim3(256), B256, 0, stream>>>(w_ffn2, wffn2T,  512,  4, 0);
  // 1. x (B,512,4096) f32 -> xt (B,4096,512) bf16
  transpose_in<<<dim3(64, 8, 8), B256, 0, stream>>>(x, xt);
  // 2+3. per-chunk: qkvH = xt_chunk @ w_qkv + b_qkv; attnO_chunk = blockattn
  for (int c = 0; c < nq; ++c) {
    gemm_kernel<false><<<dim3(6 * (QCH / 128)), B256, 0, stream>>>(
        xt + (size_t)c * QCH * 512, wqkvT, b_qkv, nullptr, nullptr, nullptr,
        qkvH, 1536, 512, 6);
    attn_kernel<<<dim3(QCH / 64 * 8), B256, 0, stream>>>(
        qkvH, attnO + (size_t)c * QCH * 512);
  }
  // 4. ares = (attnO @ w_proj + b_proj) * attn_scale + attn_bias + xt
  gemm_kernel<true><<<dim3(2 * (NTOK / 128)), B256, 0, stream>>>(
      attnO, wprojT, b_proj, attn_scale, attn_bias, xt, ares, 512, 512, 2);
  // 5. h = LN1(ares)   (hbuf overwrites attnO region; attnO dead)
  ln_kernel<<<dim3(NTOK / 4), B256, 0, stream>>>(ares, ln1_g, ln1_b, hbuf);
  // 6-9. per ffn chunk: ffn1+glu -> ffn2(+res) -> LN2 stats -> out
  for (int c = 0; c < nf; ++c) {
    const unsigned short* hC = hbuf + (size_t)c * FCHf * 512;
    ffn1glu_kernel<<<dim3(8 * (FCHf / 128)), B256, 0, stream>>>(
        hC, wffn1T, b_ffn1, gbuf, 8);
    gemm_kernel<true><<<dim3(2 * (FCHf / 128)), B256, 0, stream>>>(
        gbuf, wffn2T, b_ffn2, mlp_scale, mlp_bias, hC, mres, 512, 1024, 2);
    ln_stats<<<dim3(FCHf / 4), B256, 0, stream>>>(mres, st2);
    transpose_norm<<<dim3(8, 64, FCHf / 4096), B256, 0, stream>>>(
        mres, st2, ln2_g, ln2_b, (float*)d_out, c * (FCHf / 4096));
  }
}